// Round 21
// baseline (293.481 us; speedup 1.0000x reference)
//
#include <hip/hip_runtime.h>
#include <hip/hip_bf16.h>
#include <math.h>

#define BB 256
#define TT 512
#define DIN 64
#define ZZ 32
#define HH 64
#define NITEMS 8192   // 8 k-levels * 256 batches * 4 wave-slots

typedef __attribute__((ext_vector_type(4))) float f32x4;
typedef __attribute__((ext_vector_type(8))) __bf16 bf16x8;
typedef __attribute__((ext_vector_type(4))) __bf16 bf16x4;
typedef __attribute__((ext_vector_type(2))) unsigned int u32x2;
typedef __attribute__((ext_vector_type(4))) unsigned int u32x4;
typedef unsigned long long u64;

union FragU { u32x4 u; bf16x8 b; };
union HalfU { bf16x4 b; u32x2 u; };
union VecU  { f32x4 f; u64 u[2]; };

__device__ __forceinline__ f32x4 mfma16(bf16x8 a, bf16x8 b, f32x4 c) {
  return __builtin_amdgcn_mfma_f32_16x16x32_bf16(a, b, c, 0, 0, 0);
}

__device__ __forceinline__ float elu1(float v) {
  return fminf(v, __expf(v) - 1.f);
}
__device__ __forceinline__ f32x4 elu4(f32x4 v) {
  f32x4 r;
  r.x = elu1(v.x); r.y = elu1(v.y); r.z = elu1(v.z); r.w = elu1(v.w);
  return r;
}

__device__ __forceinline__ bf16x8 pack2(f32x4 a, f32x4 b) {
  bf16x8 r;
  r[0] = (__bf16)a.x; r[1] = (__bf16)a.y; r[2] = (__bf16)a.z; r[3] = (__bf16)a.w;
  r[4] = (__bf16)b.x; r[5] = (__bf16)b.y; r[6] = (__bf16)b.z; r[7] = (__bf16)b.w;
  return r;
}

__device__ __forceinline__ void packhl(f32x4 a, f32x4 b, bf16x8& hi, bf16x8& lo) {
  hi = pack2(a, b);
  f32x4 ra, rb;
  ra.x = (float)hi[0]; ra.y = (float)hi[1]; ra.z = (float)hi[2]; ra.w = (float)hi[3];
  rb.x = (float)hi[4]; rb.y = (float)hi[5]; rb.z = (float)hi[6]; rb.w = (float)hi[7];
  lo = pack2(a - ra, b - rb);
}

__device__ __forceinline__ bf16x8 ldw(const float* rowp, int o1, int o2) {
  f32x4 a = *reinterpret_cast<const f32x4*>(rowp + o1);
  f32x4 b = *reinterpret_cast<const f32x4*>(rowp + o2);
  return pack2(a, b);
}
__device__ __forceinline__ void ldw2(const float* rowp, int o1, int o2,
                                     bf16x8& hi, bf16x8& lo) {
  f32x4 a = *reinterpret_cast<const f32x4*>(rowp + o1);
  f32x4 b = *reinterpret_cast<const f32x4*>(rowp + o2);
  packhl(a, b, hi, lo);
}

__device__ __forceinline__ float tanh1(float x) {
  float t = __expf(2.f * x);
  return fmaf(-2.f, __builtin_amdgcn_rcpf(t + 1.f), 1.f);
}
__device__ __forceinline__ f32x4 tanh4(f32x4 v) {
  f32x4 r;
  r.x = tanh1(v.x); r.y = tanh1(v.y); r.z = tanh1(v.z); r.w = tanh1(v.w);
  return r;
}

// coherence-point (sc1) store/load of 8B, relaxed agent scope.
__device__ __forceinline__ void cp_store8(u64* p, u64 v) {
  __hip_atomic_store(p, v, __ATOMIC_RELAXED, __HIP_MEMORY_SCOPE_AGENT);
}
__device__ __forceinline__ u64 cp_load8(const u64* p) {
  return __hip_atomic_load(p, __ATOMIC_RELAXED, __HIP_MEMORY_SCOPE_AGENT);
}

// chain ch's progress flag: rnn batch (16*ch), row 0 -- never used for data.
__device__ __forceinline__ int* chain_flag(float* rnn, int ch) {
  return (int*)(rnn + (size_t)(ch * 16) * TT * ZZ);
}

// ---------------------------------------------------------------------------
// prep_kernel: P0[b,t] = (bi0+bh0) + x[b,t] @ Wi0^T for all 131072 rows,
// plus global flag/counter init (block 0). Verbatim R13.
// ---------------------------------------------------------------------------
__global__ __launch_bounds__(256, 2) void prep_kernel(
    const float* __restrict__ x,
    const float* __restrict__ Wi0,
    const float* __restrict__ bi0, const float* __restrict__ bh0,
    float* __restrict__ p0, float* __restrict__ rnn)
{
  if (blockIdx.x == 0) {
    const int t = threadIdx.x;
    if (t < 16) *chain_flag(rnn, t) = 0;
    if (t == 16) *((int*)(rnn + (size_t)TT * ZZ)) = 0;   // work counter
  }
  const int lane = threadIdx.x & 63;
  const int wv = threadIdx.x >> 6;
  const int q = lane >> 4, c = lane & 15;

  bf16x8 Wh[2][2], Wl[2][2];
  #pragma unroll
  for (int kt = 0; kt < 2; ++kt)
    #pragma unroll
    for (int mt = 0; mt < 2; ++mt)
      ldw2(Wi0 + (16 * mt + c) * 64, 32 * kt + 4 * q, 32 * kt + 16 + 4 * q,
           Wh[kt][mt], Wl[kt][mt]);
  f32x4 B0[2];
  #pragma unroll
  for (int mt = 0; mt < 2; ++mt)
    B0[mt] = *reinterpret_cast<const f32x4*>(bi0 + 16 * mt + 4 * q) +
             *reinterpret_cast<const f32x4*>(bh0 + 16 * mt + 4 * q);

  const unsigned row = blockIdx.x * 64u + (unsigned)wv * 16u + (unsigned)c;
  const float* xp = x + (size_t)row * DIN;
  f32x4 x0 = *reinterpret_cast<const f32x4*>(xp + 4 * q);
  f32x4 x1 = *reinterpret_cast<const f32x4*>(xp + 16 + 4 * q);
  f32x4 x2 = *reinterpret_cast<const f32x4*>(xp + 32 + 4 * q);
  f32x4 x3 = *reinterpret_cast<const f32x4*>(xp + 48 + 4 * q);
  bf16x8 xf0 = pack2(x0, x1), xf1 = pack2(x2, x3);

  float* pout = p0 + (size_t)row * ZZ;
  #pragma unroll
  for (int mt = 0; mt < 2; ++mt) {
    f32x4 a = mfma16(Wh[0][mt], xf0, B0[mt]);
    a = mfma16(Wl[0][mt], xf0, a);
    a = mfma16(Wh[1][mt], xf1, a);
    a = mfma16(Wl[1][mt], xf1, a);
    *reinterpret_cast<f32x4*>(pout + 16 * mt + 4 * q) = a;
  }
}

// ---------------------------------------------------------------------------
// fused_kernel v11: barrier-free 2-wave chain pipeline.
// Chain blocks (0..15): wave0 = D (layer-0, register-resident recurrence,
// 6 MFMA/step, writes z0 to an 8-slot LDS ring), wave1 = E (layer-1, one
// step behind, consumes ring, publishes global flags). Flow control via LDS
// prod/econs flags + workgroup acquire/release fences. Waves 2-7 become
// workers immediately after one init barrier; D/E join when done.
// Worker role verbatim R13.
// ---------------------------------------------------------------------------
__global__ __launch_bounds__(512, 1) void fused_kernel(
    const float* __restrict__ p0buf,
    const float* __restrict__ Wh0,
    const float* __restrict__ Wi1, const float* __restrict__ Wh1,
    const float* __restrict__ bi1, const float* __restrict__ bh1,
    const float* __restrict__ h0g,
    const float* __restrict__ w1, const float* __restrict__ b1,
    const float* __restrict__ w2, const float* __restrict__ b2,
    const float* __restrict__ w3, const float* __restrict__ b3,
    float* __restrict__ rnn, float* __restrict__ out)
{
  // [0]=prod flag, [32]=econs flag, ring at +64 ints:
  // slot k (k=0..7): zh at u32x4 index k*128 + lane, zl at k*128 + 64 + lane.
  __shared__ __align__(16) unsigned int lds_all[64 + 8 * 128 * 4];
  int* prod  = (int*)&lds_all[0];
  int* econs = (int*)&lds_all[32];
  u32x4* ring = reinterpret_cast<u32x4*>(&lds_all[64]);

  const int lane = threadIdx.x & 63;
  const int wv = threadIdx.x >> 6;     // 0..7
  const int q = lane >> 4, c = lane & 15;
  const f32x4 Z4 = {0.f, 0.f, 0.f, 0.f};

  if (blockIdx.x < 16) {
    if (threadIdx.x == 0) { *prod = -1; *econs = -1; }
    __syncthreads();                   // one-time init barrier (all 8 waves)

    const int ch = blockIdx.x;
    const int b0 = ch * 16;

    if (wv == 0) {
      // =============== D wave: layer 0, both tiles, register state ===============
      __builtin_amdgcn_s_setprio(1);
      const float* pp = p0buf + (size_t)(b0 + c) * TT * ZZ;
      bf16x8 W0h[2], W0l[2];
      #pragma unroll
      for (int mt = 0; mt < 2; ++mt)
        ldw2(Wh0 + (16 * mt + c) * 32, 4 * q, 16 + 4 * q, W0h[mt], W0l[mt]);
      bf16x8 zh0, zl0;
      {
        f32x4 u0 = *reinterpret_cast<const f32x4*>(h0g + 4 * q);
        f32x4 u1 = *reinterpret_cast<const f32x4*>(h0g + 16 + 4 * q);
        packhl(u0, u1, zh0, zl0);
      }
      auto ldp = [&](int t, f32x4& m0, f32x4& m1) {
        const float* pt = pp + (size_t)t * ZZ;
        m0 = *reinterpret_cast<const f32x4*>(pt + 4 * q);
        m1 = *reinterpret_cast<const f32x4*>(pt + 16 + 4 * q);
      };
      f32x4 Pa0, Pa1, Pb0, Pb1, Pc0, Pc1;
      ldp(511, Pa0, Pa1); ldp(510, Pb0, Pb1); ldp(509, Pc0, Pc1);

      int ec = -1;
      auto DSTEP = [&](int s, f32x4& Pm0, f32x4& Pm1) {
        if (ec < s - 8) {
          do {
            ec = __hip_atomic_load(econs, __ATOMIC_ACQUIRE,
                                   __HIP_MEMORY_SCOPE_WORKGROUP);
            if (ec < s - 8) __builtin_amdgcn_s_sleep(1);
          } while (ec < s - 8);
        }
        f32x4 dm0 = mfma16(W0h[0], zh0, Pm0);
        f32x4 dm1 = mfma16(W0h[1], zh0, Pm1);
        f32x4 dl0 = mfma16(W0l[0], zh0, mfma16(W0h[0], zl0, Z4));
        f32x4 dl1 = mfma16(W0l[1], zh0, mfma16(W0h[1], zl0, Z4));
        {
          const int t = 511 - s;
          const int tl = t >= 3 ? t - 3 : 0;
          ldp(tl, Pm0, Pm1);
        }
        f32x4 d0 = tanh4(dm0 + dl0), d1 = tanh4(dm1 + dl1);
        packhl(d0, d1, zh0, zl0);
        FragU fh, fl; fh.b = zh0; fl.b = zl0;
        const int base = (s & 7) * 128;
        ring[base + lane] = fh.u;
        ring[base + 64 + lane] = fl.u;
        __builtin_amdgcn_fence(__ATOMIC_RELEASE, "workgroup");
        __hip_atomic_store(prod, s, __ATOMIC_RELAXED,
                           __HIP_MEMORY_SCOPE_WORKGROUP);
      };

      #pragma unroll 1
      for (int g = 0; g < 170; ++g) {      // s = 0..509
        DSTEP(3 * g, Pa0, Pa1);
        DSTEP(3 * g + 1, Pb0, Pb1);
        DSTEP(3 * g + 2, Pc0, Pc1);
      }
      DSTEP(510, Pa0, Pa1);                // s = 510 (last needed output)
      __builtin_amdgcn_s_setprio(0);
    } else if (wv == 1) {
      // =============== E wave: layer 1, both tiles, one step behind ===============
      __builtin_amdgcn_s_setprio(1);
      float* pr = rnn + (size_t)(b0 + c) * TT * ZZ;
      float* po = out + (size_t)(b0 + c) * TT * ZZ;
      int* flg = chain_flag(rnn, ch);

      bf16x8 W1h[2][2], W1l[2][2];   // [kt][mt]; kt0 = Wi1, kt1 = Wh1
      #pragma unroll
      for (int mt = 0; mt < 2; ++mt) {
        ldw2(Wi1 + (16 * mt + c) * 32, 4 * q, 16 + 4 * q, W1h[0][mt], W1l[0][mt]);
        ldw2(Wh1 + (16 * mt + c) * 32, 4 * q, 16 + 4 * q, W1h[1][mt], W1l[1][mt]);
      }
      f32x4 B1[2];
      #pragma unroll
      for (int mt = 0; mt < 2; ++mt)
        B1[mt] = *reinterpret_cast<const f32x4*>(bi1 + 16 * mt + 4 * q) +
                 *reinterpret_cast<const f32x4*>(bh1 + 16 * mt + 4 * q);
      bf16x8 zh1, zl1;
      {
        f32x4 u0 = *reinterpret_cast<const f32x4*>(h0g + 32 + 4 * q);
        f32x4 u1 = *reinterpret_cast<const f32x4*>(h0g + 48 + 4 * q);
        packhl(u0, u1, zh1, zl1);
      }

      // pre-loop: fetch z0 for step 1 (= D output 0, slot 0)
      int fv = __hip_atomic_load(prod, __ATOMIC_ACQUIRE,
                                 __HIP_MEMORY_SCOPE_WORKGROUP);
      while (fv < 0) {
        __builtin_amdgcn_s_sleep(1);
        fv = __hip_atomic_load(prod, __ATOMIC_ACQUIRE,
                               __HIP_MEMORY_SCOPE_WORKGROUP);
      }
      FragU zh0c, zl0c;
      zh0c.u = ring[lane];
      zl0c.u = ring[64 + lane];

      #pragma unroll 1
      for (int s = 1; s <= 511; ++s) {
        int fq = 0x7fffffff;
        if (s < 511)
          fq = __hip_atomic_load(prod, __ATOMIC_RELAXED,
                                 __HIP_MEMORY_SCOPE_WORKGROUP);
        // signal slot s-1 consumed (release orders the prior ring reads)
        __builtin_amdgcn_fence(__ATOMIC_RELEASE, "workgroup");
        __hip_atomic_store(econs, s - 1, __ATOMIC_RELAXED,
                           __HIP_MEMORY_SCOPE_WORKGROUP);

        f32x4 ea0 = mfma16(W1h[1][0], zh1, mfma16(W1h[0][0], zh0c.b, B1[0]));
        f32x4 eb0 = mfma16(W1h[1][0], zl1, mfma16(W1h[0][0], zl0c.b, Z4));
        f32x4 ec0 = mfma16(W1l[1][0], zh1, mfma16(W1l[0][0], zh0c.b, Z4));
        f32x4 ea1 = mfma16(W1h[1][1], zh1, mfma16(W1h[0][1], zh0c.b, B1[1]));
        f32x4 eb1 = mfma16(W1h[1][1], zl1, mfma16(W1h[0][1], zl0c.b, Z4));
        f32x4 ec1 = mfma16(W1l[1][1], zh1, mfma16(W1l[0][1], zh0c.b, Z4));
        f32x4 e0 = tanh4(ea0 + (eb0 + ec0));
        f32x4 e1 = tanh4(ea1 + (eb1 + ec1));
        const int t = 511 - s;
        {
          VecU cv; cv.f = e0;
          u64* dp = reinterpret_cast<u64*>(pr + (size_t)(t + 1) * ZZ + 4 * q);
          cp_store8(dp, cv.u[0]); cp_store8(dp + 1, cv.u[1]);
          cv.f = e1;
          dp = reinterpret_cast<u64*>(pr + (size_t)(t + 1) * ZZ + 16 + 4 * q);
          cp_store8(dp, cv.u[0]); cp_store8(dp + 1, cv.u[1]);
        }
        if (t == 510) {
          float* pot = po + (size_t)511 * ZZ;
          *reinterpret_cast<f32x4*>(pot + 4 * q) = e0;
          *reinterpret_cast<f32x4*>(pot + 16 + 4 * q) = e1;
        }
        packhl(e0, e1, zh1, zl1);
        if (s < 511) {
          while (fq < s) {
            fq = __hip_atomic_load(prod, __ATOMIC_ACQUIRE,
                                   __HIP_MEMORY_SCOPE_WORKGROUP);
          }
          __builtin_amdgcn_fence(__ATOMIC_ACQUIRE, "workgroup");
          const int base = (s & 7) * 128;
          zh0c.u = ring[base + lane];
          zl0c.u = ring[base + 64 + lane];
        }
        if (((s & 15) == 0) || s == 511) {
          asm volatile("s_waitcnt vmcnt(0)" ::: "memory");
          if (lane == 0)
            __hip_atomic_store(flg, s, __ATOMIC_RELAXED,
                               __HIP_MEMORY_SCOPE_AGENT);
        }
      }
      __builtin_amdgcn_s_setprio(0);
    }
    // waves 2..7 arrive here immediately; D/E arrive when the chain is done.
  }

  // =================== ODE worker role (verbatim R13 math) ===================
  bf16x8 W1[4], W2[2][4], W3[2][2];
  f32x4 BZ1[4], BZ2[4], BZ3[2];
  #pragma unroll
  for (int mt = 0; mt < 4; ++mt) {
    W1[mt] = ldw(w1 + (16 * mt + c) * 32, 4 * q, 16 + 4 * q);
    BZ1[mt] = *reinterpret_cast<const f32x4*>(b1 + 16 * mt + 4 * q);
    BZ2[mt] = *reinterpret_cast<const f32x4*>(b2 + 16 * mt + 4 * q);
  }
  #pragma unroll
  for (int kt = 0; kt < 2; ++kt)
    #pragma unroll
    for (int mt = 0; mt < 4; ++mt)
      W2[kt][mt] = ldw(w2 + (16 * mt + c) * 64, 32 * kt + 4 * q, 32 * kt + 16 + 4 * q);
  #pragma unroll
  for (int kt = 0; kt < 2; ++kt)
    #pragma unroll
    for (int mt = 0; mt < 2; ++mt)
      W3[kt][mt] = ldw(w3 + (16 * mt + c) * 64, 32 * kt + 4 * q, 32 * kt + 16 + 4 * q);
  #pragma unroll
  for (int mt = 0; mt < 2; ++mt)
    BZ3[mt] = *reinterpret_cast<const f32x4*>(b3 + 16 * mt + 4 * q);

  auto feval = [&](bf16x8 xf, f32x4& o0, f32x4& o1) {
    f32x4 a[4];
    #pragma unroll
    for (int mt = 0; mt < 4; ++mt) a[mt] = mfma16(W1[mt], xf, BZ1[mt]);
    #pragma unroll
    for (int mt = 0; mt < 4; ++mt) a[mt] = elu4(a[mt]);
    bf16x8 h10 = pack2(a[0], a[1]), h11 = pack2(a[2], a[3]);
    f32x4 g[4];
    #pragma unroll
    for (int mt = 0; mt < 4; ++mt)
      g[mt] = mfma16(W2[1][mt], h11, mfma16(W2[0][mt], h10, BZ2[mt]));
    #pragma unroll
    for (int mt = 0; mt < 4; ++mt) g[mt] = elu4(g[mt]);
    bf16x8 h20 = pack2(g[0], g[1]), h21 = pack2(g[2], g[3]);
    o0 = mfma16(W3[1][0], h21, mfma16(W3[0][0], h20, BZ3[0]));
    o1 = mfma16(W3[1][1], h21, mfma16(W3[0][1], h20, BZ3[1]));
  };

  int* ctr = (int*)(rnn + (size_t)TT * ZZ);   // batch 1 row 0 (never data)
  const float hs = 0.01f;

  for (;;) {
    int n0 = 0;
    if (lane == 0)
      n0 = __hip_atomic_fetch_add(ctr, 1, __ATOMIC_RELAXED,
                                  __HIP_MEMORY_SCOPE_AGENT);
    const int n = __shfl(n0, 0);
    if (n >= NITEMS) break;

    const int k7 = n >> 10;            // 0..7, high-t' first
    const int rem = n & 1023;
    const int bb = rem >> 2;           // batch
    const int widx = rem & 3;          // wave slot within k-level
    const int tp = 510 - (64 * k7 + 16 * widx + c);   // may be -1 (1 lane)
    const int ch = bb >> 4;
    int need = 16 + 64 * k7 + 16 * widx;
    if (need > 511) need = 511;

    int* flg = chain_flag(rnn, ch);
    while (__hip_atomic_load(flg, __ATOMIC_RELAXED,
                             __HIP_MEMORY_SCOPE_AGENT) < need)
      __builtin_amdgcn_s_sleep(32);

    const int tpc = tp < 0 ? 0 : tp;
    const u64* sp = reinterpret_cast<const u64*>(
        rnn + ((size_t)bb * TT + tpc + 1) * ZZ);
    VecU c0, c1;
    c0.u[0] = cp_load8(sp + 2 * q);
    c0.u[1] = cp_load8(sp + 2 * q + 1);
    c1.u[0] = cp_load8(sp + 8 + 2 * q);
    c1.u[1] = cp_load8(sp + 8 + 2 * q + 1);
    f32x4 y0 = c0.f;
    f32x4 y1 = c1.f;

    f32x4 k0, k1, ks0, ks1;
    #pragma unroll 1
    for (int it = 0; it < 9; ++it) {
      feval(pack2(y0, y1), k0, k1);
      ks0 = k0; ks1 = k1;
      feval(pack2(y0 + (0.5f * hs) * k0, y1 + (0.5f * hs) * k1), k0, k1);
      ks0 += 2.f * k0; ks1 += 2.f * k1;
      feval(pack2(y0 + (0.5f * hs) * k0, y1 + (0.5f * hs) * k1), k0, k1);
      ks0 += 2.f * k0; ks1 += 2.f * k1;
      feval(pack2(y0 + hs * k0, y1 + hs * k1), k0, k1);
      y0 += (hs / 6.f) * (ks0 + k0);
      y1 += (hs / 6.f) * (ks1 + k1);
    }

    if (tp >= 0) {
      float* dstp = out + ((size_t)bb * TT + tp) * ZZ;
      *reinterpret_cast<f32x4*>(dstp + 4 * q) = y0;
      *reinterpret_cast<f32x4*>(dstp + 16 + 4 * q) = y1;
    }
  }
}

// ---------------------------------------------------------------------------
extern "C" void kernel_launch(void* const* d_in, const int* in_sizes, int n_in,
                              void* d_out, int out_size, void* d_ws, size_t ws_size,
                              hipStream_t stream) {
  const float* x   = (const float*)d_in[0];
  const float* Wi0 = (const float*)d_in[1];
  const float* Wh0 = (const float*)d_in[2];
  const float* bi0 = (const float*)d_in[3];
  const float* bh0 = (const float*)d_in[4];
  const float* Wi1 = (const float*)d_in[5];
  const float* Wh1 = (const float*)d_in[6];
  const float* bi1 = (const float*)d_in[7];
  const float* bh1 = (const float*)d_in[8];
  const float* h0  = (const float*)d_in[9];
  const float* w1  = (const float*)d_in[10];
  const float* b1  = (const float*)d_in[11];
  const float* w2  = (const float*)d_in[12];
  const float* b2  = (const float*)d_in[13];
  const float* w3  = (const float*)d_in[14];
  const float* b3  = (const float*)d_in[15];
  float* out = (float*)d_out;
  float* rnn = (float*)d_ws;      // B*T*Z fp32 scratch; row 0 of selected
                                  // batches doubles as sync flags/counter
  float* p0  = (float*)d_out;     // d_out doubles as P0 scratch (disjoint
                                  // from fused-kernel out writes, proven)

  prep_kernel<<<2048, 256, 0, stream>>>(x, Wi0, bi0, bh0, p0, rnn);
  // 256 blocks x 512 threads; chain blocks use a barrier-free 2-wave
  // D->E pipeline (LDS ring + fences), everything else is workers.
  fused_kernel<<<256, 512, 0, stream>>>(p0, Wh0, Wi1, Wh1, bi1, bh1, h0,
                                        w1, b1, w2, b2, w3, b3, rnn, out);
}

// Round 22
// 223.332 us; speedup vs baseline: 1.3141x; 1.3141x over previous
//
#include <hip/hip_runtime.h>
#include <hip/hip_bf16.h>
#include <math.h>

#define BB 256
#define TT 512
#define DIN 64
#define ZZ 32
#define HH 64
#define NITEMS 8192   // 8 k-levels * 256 batches * 4 wave-slots
#define NBAR 513      // barriers per chain role (verified count)
#define SHROW 3072    // inflated row: LDS = 2*4*3072*4B = 96KB -> 1 block/CU

typedef __attribute__((ext_vector_type(4))) float f32x4;
typedef __attribute__((ext_vector_type(8))) __bf16 bf16x8;
typedef __attribute__((ext_vector_type(4))) __bf16 bf16x4;
typedef __attribute__((ext_vector_type(2))) unsigned int u32x2;
typedef __attribute__((ext_vector_type(4))) unsigned int u32x4;
typedef unsigned long long u64;

union FragU { u32x4 u; bf16x8 b; };
union HalfU { bf16x4 b; u32x2 u; };
union VecU  { f32x4 f; u64 u[2]; };

__device__ __forceinline__ f32x4 mfma16(bf16x8 a, bf16x8 b, f32x4 c) {
  return __builtin_amdgcn_mfma_f32_16x16x32_bf16(a, b, c, 0, 0, 0);
}

__device__ __forceinline__ float elu1(float v) {
  return fminf(v, __expf(v) - 1.f);
}
__device__ __forceinline__ f32x4 elu4(f32x4 v) {
  f32x4 r;
  r.x = elu1(v.x); r.y = elu1(v.y); r.z = elu1(v.z); r.w = elu1(v.w);
  return r;
}

__device__ __forceinline__ bf16x8 pack2(f32x4 a, f32x4 b) {
  bf16x8 r;
  r[0] = (__bf16)a.x; r[1] = (__bf16)a.y; r[2] = (__bf16)a.z; r[3] = (__bf16)a.w;
  r[4] = (__bf16)b.x; r[5] = (__bf16)b.y; r[6] = (__bf16)b.z; r[7] = (__bf16)b.w;
  return r;
}

__device__ __forceinline__ void packhl(f32x4 a, f32x4 b, bf16x8& hi, bf16x8& lo) {
  hi = pack2(a, b);
  f32x4 ra, rb;
  ra.x = (float)hi[0]; ra.y = (float)hi[1]; ra.z = (float)hi[2]; ra.w = (float)hi[3];
  rb.x = (float)hi[4]; rb.y = (float)hi[5]; rb.z = (float)hi[6]; rb.w = (float)hi[7];
  lo = pack2(a - ra, b - rb);
}

__device__ __forceinline__ void packh2(f32x4 v, u32x2& hi, u32x2& lo) {
  HalfU H, L;
  H.b[0] = (__bf16)v.x; H.b[1] = (__bf16)v.y;
  H.b[2] = (__bf16)v.z; H.b[3] = (__bf16)v.w;
  f32x4 r;
  r.x = (float)H.b[0]; r.y = (float)H.b[1];
  r.z = (float)H.b[2]; r.w = (float)H.b[3];
  f32x4 d = v - r;
  L.b[0] = (__bf16)d.x; L.b[1] = (__bf16)d.y;
  L.b[2] = (__bf16)d.z; L.b[3] = (__bf16)d.w;
  hi = H.u; lo = L.u;
}

__device__ __forceinline__ bf16x8 ldw(const float* rowp, int o1, int o2) {
  f32x4 a = *reinterpret_cast<const f32x4*>(rowp + o1);
  f32x4 b = *reinterpret_cast<const f32x4*>(rowp + o2);
  return pack2(a, b);
}
__device__ __forceinline__ void ldw2(const float* rowp, int o1, int o2,
                                     bf16x8& hi, bf16x8& lo) {
  f32x4 a = *reinterpret_cast<const f32x4*>(rowp + o1);
  f32x4 b = *reinterpret_cast<const f32x4*>(rowp + o2);
  packhl(a, b, hi, lo);
}

__device__ __forceinline__ float tanh1(float x) {
  float t = __expf(2.f * x);
  return fmaf(-2.f, __builtin_amdgcn_rcpf(t + 1.f), 1.f);
}
__device__ __forceinline__ f32x4 tanh4(f32x4 v) {
  f32x4 r;
  r.x = tanh1(v.x); r.y = tanh1(v.y); r.z = tanh1(v.z); r.w = tanh1(v.w);
  return r;
}

// raw barrier: waits LDS ops only; vmcnt stays in flight across it.
#define STEP_BARRIER() asm volatile("s_waitcnt lgkmcnt(0)\ns_barrier" ::: "memory")

// coherence-point (sc1) store/load of 8B, relaxed agent scope.
__device__ __forceinline__ void cp_store8(u64* p, u64 v) {
  __hip_atomic_store(p, v, __ATOMIC_RELAXED, __HIP_MEMORY_SCOPE_AGENT);
}
__device__ __forceinline__ u64 cp_load8(const u64* p) {
  return __hip_atomic_load(p, __ATOMIC_RELAXED, __HIP_MEMORY_SCOPE_AGENT);
}

// chain ch's progress flag: rnn batch (16*ch), row 0 -- never used for data.
__device__ __forceinline__ int* chain_flag(float* rnn, int ch) {
  return (int*)(rnn + (size_t)(ch * 16) * TT * ZZ);
}

// ---------------------------------------------------------------------------
// prep_kernel: P0[b,t] = (bi0+bh0) + x[b,t] @ Wi0^T for all 131072 rows,
// plus flag/counter init (block 0).
// ---------------------------------------------------------------------------
__global__ __launch_bounds__(256, 2) void prep_kernel(
    const float* __restrict__ x,
    const float* __restrict__ Wi0,
    const float* __restrict__ bi0, const float* __restrict__ bh0,
    float* __restrict__ p0, float* __restrict__ rnn)
{
  if (blockIdx.x == 0) {
    const int t = threadIdx.x;
    if (t < 16) *chain_flag(rnn, t) = 0;
    if (t == 16) *((int*)(rnn + (size_t)TT * ZZ)) = 0;   // work counter
  }
  const int lane = threadIdx.x & 63;
  const int wv = threadIdx.x >> 6;
  const int q = lane >> 4, c = lane & 15;

  bf16x8 Wh[2][2], Wl[2][2];
  #pragma unroll
  for (int kt = 0; kt < 2; ++kt)
    #pragma unroll
    for (int mt = 0; mt < 2; ++mt)
      ldw2(Wi0 + (16 * mt + c) * 64, 32 * kt + 4 * q, 32 * kt + 16 + 4 * q,
           Wh[kt][mt], Wl[kt][mt]);
  f32x4 B0[2];
  #pragma unroll
  for (int mt = 0; mt < 2; ++mt)
    B0[mt] = *reinterpret_cast<const f32x4*>(bi0 + 16 * mt + 4 * q) +
             *reinterpret_cast<const f32x4*>(bh0 + 16 * mt + 4 * q);

  const unsigned row = blockIdx.x * 64u + (unsigned)wv * 16u + (unsigned)c;
  const float* xp = x + (size_t)row * DIN;
  f32x4 x0 = *reinterpret_cast<const f32x4*>(xp + 4 * q);
  f32x4 x1 = *reinterpret_cast<const f32x4*>(xp + 16 + 4 * q);
  f32x4 x2 = *reinterpret_cast<const f32x4*>(xp + 32 + 4 * q);
  f32x4 x3 = *reinterpret_cast<const f32x4*>(xp + 48 + 4 * q);
  bf16x8 xf0 = pack2(x0, x1), xf1 = pack2(x2, x3);

  float* pout = p0 + (size_t)row * ZZ;
  #pragma unroll
  for (int mt = 0; mt < 2; ++mt) {
    f32x4 a = mfma16(Wh[0][mt], xf0, B0[mt]);
    a = mfma16(Wl[0][mt], xf0, a);
    a = mfma16(Wh[1][mt], xf1, a);
    a = mfma16(Wl[1][mt], xf1, a);
    *reinterpret_cast<f32x4*>(pout + 16 * mt + 4 * q) = a;
  }
}

// ---------------------------------------------------------------------------
// fused_kernel (R16, session best): blocks 0..15 = 4-wave rnn chains with
// 96 KB LDS footprint -> exactly 1 block/CU; blocks 16..255 = ode workers
// (per-wave work stealing, sc1 data path, relaxed flag polls).
// ---------------------------------------------------------------------------
__global__ __launch_bounds__(512, 1) void fused_kernel(
    const float* __restrict__ p0buf,
    const float* __restrict__ Wh0,
    const float* __restrict__ Wi1, const float* __restrict__ Wh1,
    const float* __restrict__ bi1, const float* __restrict__ bh1,
    const float* __restrict__ h0g,
    const float* __restrict__ w1, const float* __restrict__ b1,
    const float* __restrict__ w2, const float* __restrict__ b2,
    const float* __restrict__ w3, const float* __restrict__ b3,
    float* __restrict__ rnn, float* __restrict__ out)
{
  // 2*4*SHROW u32 = 96 KB static LDS: only [.][.][0..255] is ever touched;
  // the size exists purely to cap occupancy at 1 block/CU.
  __shared__ __align__(16) unsigned int sh[2][4][SHROW];
  const int lane = threadIdx.x & 63;
  const int wv = threadIdx.x >> 6;     // 0..7
  const int q = lane >> 4, c = lane & 15;
  const f32x4 Z4 = {0.f, 0.f, 0.f, 0.f};

  if (blockIdx.x < 16) {
    // =================== RNN chain block ===================
    if (wv >= 4) {           // idle waves: match the chain's 513 barriers
      for (int i = 0; i < NBAR; ++i) STEP_BARRIER();
      return;
    }
    __builtin_amdgcn_s_setprio(1);
    const int ch = blockIdx.x;
    const int b0 = ch * 16;

    const float* pp = p0buf + (size_t)(b0 + c) * TT * ZZ;
    float* pr = rnn + (size_t)(b0 + c) * TT * ZZ;
    float* po = out + (size_t)(b0 + c) * TT * ZZ;
    int* flg = chain_flag(rnn, ch);

    const int mt = wv & 1;
    const int dwoff = lane * 4 + mt * 2;

    if (wv < 2) {
      // ---- d-wave: layer 0, tile mt ----  (1 + 512 barriers)
      bf16x8 W0h, W0l;
      ldw2(Wh0 + (16 * mt + c) * 32, 4 * q, 16 + 4 * q, W0h, W0l);
      const float* ppt = pp + 16 * mt + 4 * q;

      {
        f32x4 u = *reinterpret_cast<const f32x4*>(h0g + 16 * mt + 4 * q);
        u32x2 hi, lo;
        packh2(u, hi, lo);
        *reinterpret_cast<u32x2*>(&sh[0][0][dwoff]) = hi;
        *reinterpret_cast<u32x2*>(&sh[0][1][dwoff]) = lo;
      }
      f32x4 Pa = *reinterpret_cast<const f32x4*>(ppt + (size_t)511 * ZZ);
      f32x4 Pb = *reinterpret_cast<const f32x4*>(ppt + (size_t)510 * ZZ);
      f32x4 Pc = *reinterpret_cast<const f32x4*>(ppt + (size_t)509 * ZZ);

      STEP_BARRIER();

      auto DSTEP = [&](int s, f32x4& Pm) {
        const int cur = s & 1;
        FragU z0, z1;
        z0.u = *reinterpret_cast<const u32x4*>(&sh[cur][0][lane * 4]);
        z1.u = *reinterpret_cast<const u32x4*>(&sh[cur][1][lane * 4]);
        f32x4 dm = mfma16(W0h, z0.b, Pm);
        f32x4 dl = mfma16(W0l, z0.b, mfma16(W0h, z1.b, Z4));
        {
          const int t = 511 - s;
          const int tl = t >= 3 ? t - 3 : 0;
          Pm = *reinterpret_cast<const f32x4*>(ppt + (size_t)tl * ZZ);
        }
        f32x4 d = tanh4(dm + dl);
        u32x2 hi, lo;
        packh2(d, hi, lo);
        *reinterpret_cast<u32x2*>(&sh[cur ^ 1][0][dwoff]) = hi;
        *reinterpret_cast<u32x2*>(&sh[cur ^ 1][1][dwoff]) = lo;
        STEP_BARRIER();
      };

      DSTEP(0, Pa);
      #pragma unroll 1
      for (int g = 0; g < 170; ++g) {
        DSTEP(1 + 3 * g, Pb);
        DSTEP(2 + 3 * g, Pc);
        DSTEP(3 + 3 * g, Pa);
      }
      DSTEP(511, Pb);
    } else {
      // ---- e-wave: layer 1, tile mt; publishes progress ----  (2+511 barriers)
      bf16x8 W1h0, W1l0, W1h1, W1l1;
      ldw2(Wi1 + (16 * mt + c) * 32, 4 * q, 16 + 4 * q, W1h0, W1l0);
      ldw2(Wh1 + (16 * mt + c) * 32, 4 * q, 16 + 4 * q, W1h1, W1l1);
      f32x4 B1 = *reinterpret_cast<const f32x4*>(bi1 + 16 * mt + 4 * q) +
                 *reinterpret_cast<const f32x4*>(bh1 + 16 * mt + 4 * q);

      STEP_BARRIER();

      {
        f32x4 u = *reinterpret_cast<const f32x4*>(h0g + 32 + 16 * mt + 4 * q);
        u32x2 hi, lo;
        packh2(u, hi, lo);
        *reinterpret_cast<u32x2*>(&sh[1][2][dwoff]) = hi;
        *reinterpret_cast<u32x2*>(&sh[1][3][dwoff]) = lo;
        STEP_BARRIER();
      }

      auto ESTEP = [&](int s) {
        const int cur = s & 1;
        FragU zh0, zl0, zh1, zl1;
        zh0.u = *reinterpret_cast<const u32x4*>(&sh[cur][0][lane * 4]);
        zl0.u = *reinterpret_cast<const u32x4*>(&sh[cur][1][lane * 4]);
        zh1.u = *reinterpret_cast<const u32x4*>(&sh[cur][2][lane * 4]);
        zl1.u = *reinterpret_cast<const u32x4*>(&sh[cur][3][lane * 4]);
        f32x4 ea = mfma16(W1h1, zh1.b, mfma16(W1h0, zh0.b, B1));
        f32x4 eb = mfma16(W1h1, zl1.b, mfma16(W1h0, zl0.b, Z4));
        f32x4 ec = mfma16(W1l1, zh1.b, mfma16(W1l0, zh0.b, Z4));
        f32x4 e = tanh4(ea + (eb + ec));
        const int t = 511 - s;
        // rnn store -> coherence point (sc1), visible to workers w/o fences
        {
          VecU cv; cv.f = e;
          u64* dp = reinterpret_cast<u64*>(
              pr + (size_t)(t + 1) * ZZ + 16 * mt + 4 * q);
          cp_store8(dp, cv.u[0]);
          cp_store8(dp + 1, cv.u[1]);
        }
        if (t == 510) {
          float* pot = po + (size_t)511 * ZZ + 16 * mt + 4 * q;
          *reinterpret_cast<f32x4*>(pot) = e;
        }
        u32x2 hi, lo;
        packh2(e, hi, lo);
        *reinterpret_cast<u32x2*>(&sh[cur ^ 1][2][dwoff]) = hi;
        *reinterpret_cast<u32x2*>(&sh[cur ^ 1][3][dwoff]) = lo;
        const bool upd = ((s & 15) == 0) || (s == 511);
        if (upd) asm volatile("s_waitcnt vmcnt(0)" ::: "memory");
        STEP_BARRIER();
        if (upd && mt == 0 && lane == 0)
          __hip_atomic_store(flg, s, __ATOMIC_RELAXED,
                             __HIP_MEMORY_SCOPE_AGENT);
      };

      #pragma unroll 1
      for (int g = 0; g < 170; ++g) {       // s = 1..510
        ESTEP(1 + 3 * g);
        ESTEP(2 + 3 * g);
        ESTEP(3 + 3 * g);
      }
      ESTEP(511);
    }
    return;
  }

  // =================== ODE worker block ===================
  bf16x8 W1[4], W2[2][4], W3[2][2];
  f32x4 BZ1[4], BZ2[4], BZ3[2];
  #pragma unroll
  for (int mt = 0; mt < 4; ++mt) {
    W1[mt] = ldw(w1 + (16 * mt + c) * 32, 4 * q, 16 + 4 * q);
    BZ1[mt] = *reinterpret_cast<const f32x4*>(b1 + 16 * mt + 4 * q);
    BZ2[mt] = *reinterpret_cast<const f32x4*>(b2 + 16 * mt + 4 * q);
  }
  #pragma unroll
  for (int kt = 0; kt < 2; ++kt)
    #pragma unroll
    for (int mt = 0; mt < 4; ++mt)
      W2[kt][mt] = ldw(w2 + (16 * mt + c) * 64, 32 * kt + 4 * q, 32 * kt + 16 + 4 * q);
  #pragma unroll
  for (int kt = 0; kt < 2; ++kt)
    #pragma unroll
    for (int mt = 0; mt < 2; ++mt)
      W3[kt][mt] = ldw(w3 + (16 * mt + c) * 64, 32 * kt + 4 * q, 32 * kt + 16 + 4 * q);
  #pragma unroll
  for (int mt = 0; mt < 2; ++mt)
    BZ3[mt] = *reinterpret_cast<const f32x4*>(b3 + 16 * mt + 4 * q);

  auto feval = [&](bf16x8 xf, f32x4& o0, f32x4& o1) {
    f32x4 a[4];
    #pragma unroll
    for (int mt = 0; mt < 4; ++mt) a[mt] = mfma16(W1[mt], xf, BZ1[mt]);
    #pragma unroll
    for (int mt = 0; mt < 4; ++mt) a[mt] = elu4(a[mt]);
    bf16x8 h10 = pack2(a[0], a[1]), h11 = pack2(a[2], a[3]);
    f32x4 g[4];
    #pragma unroll
    for (int mt = 0; mt < 4; ++mt)
      g[mt] = mfma16(W2[1][mt], h11, mfma16(W2[0][mt], h10, BZ2[mt]));
    #pragma unroll
    for (int mt = 0; mt < 4; ++mt) g[mt] = elu4(g[mt]);
    bf16x8 h20 = pack2(g[0], g[1]), h21 = pack2(g[2], g[3]);
    o0 = mfma16(W3[1][0], h21, mfma16(W3[0][0], h20, BZ3[0]));
    o1 = mfma16(W3[1][1], h21, mfma16(W3[0][1], h20, BZ3[1]));
  };

  int* ctr = (int*)(rnn + (size_t)TT * ZZ);   // batch 1 row 0 (never data)
  const float hs = 0.01f;

  for (;;) {
    int n0 = 0;
    if (lane == 0)
      n0 = __hip_atomic_fetch_add(ctr, 1, __ATOMIC_RELAXED,
                                  __HIP_MEMORY_SCOPE_AGENT);
    const int n = __shfl(n0, 0);
    if (n >= NITEMS) break;

    const int k7 = n >> 10;            // 0..7, high-t' first
    const int rem = n & 1023;
    const int bb = rem >> 2;           // batch
    const int widx = rem & 3;          // wave slot within k-level
    const int tp = 510 - (64 * k7 + 16 * widx + c);   // may be -1 (1 lane)
    const int ch = bb >> 4;
    int need = 16 + 64 * k7 + 16 * widx;
    if (need > 511) need = 511;

    int* flg = chain_flag(rnn, ch);
    while (__hip_atomic_load(flg, __ATOMIC_RELAXED,
                             __HIP_MEMORY_SCOPE_AGENT) < need)
      __builtin_amdgcn_s_sleep(32);

    const int tpc = tp < 0 ? 0 : tp;
    const u64* sp = reinterpret_cast<const u64*>(
        rnn + ((size_t)bb * TT + tpc + 1) * ZZ);
    VecU c0, c1;
    c0.u[0] = cp_load8(sp + 2 * q);
    c0.u[1] = cp_load8(sp + 2 * q + 1);
    c1.u[0] = cp_load8(sp + 8 + 2 * q);
    c1.u[1] = cp_load8(sp + 8 + 2 * q + 1);
    f32x4 y0 = c0.f;
    f32x4 y1 = c1.f;

    f32x4 k0, k1, ks0, ks1;
    #pragma unroll 1
    for (int it = 0; it < 9; ++it) {
      feval(pack2(y0, y1), k0, k1);
      ks0 = k0; ks1 = k1;
      feval(pack2(y0 + (0.5f * hs) * k0, y1 + (0.5f * hs) * k1), k0, k1);
      ks0 += 2.f * k0; ks1 += 2.f * k1;
      feval(pack2(y0 + (0.5f * hs) * k0, y1 + (0.5f * hs) * k1), k0, k1);
      ks0 += 2.f * k0; ks1 += 2.f * k1;
      feval(pack2(y0 + hs * k0, y1 + hs * k1), k0, k1);
      y0 += (hs / 6.f) * (ks0 + k0);
      y1 += (hs / 6.f) * (ks1 + k1);
    }

    if (tp >= 0) {
      float* dstp = out + ((size_t)bb * TT + tp) * ZZ;
      *reinterpret_cast<f32x4*>(dstp + 4 * q) = y0;
      *reinterpret_cast<f32x4*>(dstp + 16 + 4 * q) = y1;
    }
  }
}

// ---------------------------------------------------------------------------
extern "C" void kernel_launch(void* const* d_in, const int* in_sizes, int n_in,
                              void* d_out, int out_size, void* d_ws, size_t ws_size,
                              hipStream_t stream) {
  const float* x   = (const float*)d_in[0];
  const float* Wi0 = (const float*)d_in[1];
  const float* Wh0 = (const float*)d_in[2];
  const float* bi0 = (const float*)d_in[3];
  const float* bh0 = (const float*)d_in[4];
  const float* Wi1 = (const float*)d_in[5];
  const float* Wh1 = (const float*)d_in[6];
  const float* bi1 = (const float*)d_in[7];
  const float* bh1 = (const float*)d_in[8];
  const float* h0  = (const float*)d_in[9];
  const float* w1  = (const float*)d_in[10];
  const float* b1  = (const float*)d_in[11];
  const float* w2  = (const float*)d_in[12];
  const float* b2  = (const float*)d_in[13];
  const float* w3  = (const float*)d_in[14];
  const float* b3  = (const float*)d_in[15];
  float* out = (float*)d_out;
  float* rnn = (float*)d_ws;      // B*T*Z fp32 scratch; row 0 of selected
                                  // batches doubles as sync flags/counter
  float* p0  = (float*)d_out;     // d_out doubles as P0 scratch (disjoint
                                  // from fused-kernel out writes, proven)

  prep_kernel<<<2048, 256, 0, stream>>>(x, Wi0, bi0, bh0, p0, rnn);
  // 96 KB static LDS per block -> exactly 1 block/CU -> 256 blocks on 256
  // CUs, chain blocks fully isolated from worker issue traffic.
  fused_kernel<<<256, 512, 0, stream>>>(p0, Wh0, Wi1, Wh1, bi1, bh1, h0,
                                        w1, b1, w2, b2, w3, b3, rnn, out);
}